// Round 2
// baseline (9421.242 us; speedup 1.0000x reference)
//
#include <hip/hip_runtime.h>
#include <hip/hip_bf16.h>
#include <cstddef>
#include <cstdint>

// ---------------- problem constants ----------------
constexpr int B = 2, L = 2048, DIM = 2048;
constexpr int HK = 16, HV = 32, DK = 128, DV = 128;
constexpr int KEY_DIM = HK * DK;                    // 2048
constexpr int VAL_DIM = HV * DV;                    // 4096
constexpr int CONV_DIM = 2 * KEY_DIM + VAL_DIM;     // 8192
constexpr int NPROJ = CONV_DIM + VAL_DIM + HV + HV; // 12352
constexpr size_t ROWS = (size_t)B * L;              // 4096
constexpr float EPS = 1e-6f;

// workspace layout (BYTE offsets). Total ~98 MB — fits even a 128 MiB ws.
constexpr size_t OFF_QKV  = 0;                                   // bf16, 67,108,864 B
constexpr size_t OFF_Z    = OFF_QKV + ROWS * CONV_DIM * 2;       // bf16, 33,554,432 B (y in-place)
constexpr size_t OFF_A    = OFF_Z   + ROWS * VAL_DIM * 2;        // f32,  524,288 B
constexpr size_t OFF_B    = OFF_A   + ROWS * HV * 4;
constexpr size_t OFF_EG   = OFF_B   + ROWS * HV * 4;
constexpr size_t OFF_BETA = OFF_EG  + ROWS * HV * 4;
constexpr size_t WS_NEED_BYTES = OFF_BETA + ROWS * HV * 4;       // 102,760,448

// ---------------- bf16 helpers (self-contained, bit-exact) ----------------
__device__ __forceinline__ float bf2f(unsigned short u) {
    union { float f; uint32_t i; } c; c.i = ((uint32_t)u) << 16; return c.f;
}
__device__ __forceinline__ unsigned short f2bf(float f) {
    union { float f; uint32_t u; } c; c.f = f;
    uint32_t u = c.u + 0x7FFFu + ((c.u >> 16) & 1u);   // RTNE
    return (unsigned short)(u >> 16);
}

// ---------------- in-projection GEMM: [qkv|z|a|b] = x @ W^T ----------------
__device__ __forceinline__ const float* w_row_multi(int n, const float* Wq, const float* Wz,
                                                    const float* Wa, const float* Wb) {
    if (n < CONV_DIM)                return Wq + (size_t)n * DIM;
    if (n < CONV_DIM + VAL_DIM)      return Wz + (size_t)(n - CONV_DIM) * DIM;
    if (n < CONV_DIM + VAL_DIM + HV) return Wa + (size_t)(n - CONV_DIM - VAL_DIM) * DIM;
    return Wb + (size_t)(n - CONV_DIM - VAL_DIM - HV) * DIM;
}

__device__ __forceinline__ void store_multi(int m, int n, float4 v,
                                            unsigned short* qkv, unsigned short* z,
                                            float* a, float* b) {
    if (n < CONV_DIM) {
        unsigned short* p = qkv + (size_t)m * CONV_DIM + n;
        p[0] = f2bf(v.x); p[1] = f2bf(v.y); p[2] = f2bf(v.z); p[3] = f2bf(v.w);
    } else if (n < CONV_DIM + VAL_DIM) {
        unsigned short* p = z + (size_t)m * VAL_DIM + (n - CONV_DIM);
        p[0] = f2bf(v.x); p[1] = f2bf(v.y); p[2] = f2bf(v.z); p[3] = f2bf(v.w);
    } else if (n < CONV_DIM + VAL_DIM + HV) {
        *(float4*)(a + (size_t)m * HV + (n - CONV_DIM - VAL_DIM)) = v;
    } else {
        *(float4*)(b + (size_t)m * HV + (n - CONV_DIM - VAL_DIM - HV)) = v;
    }
}

__global__ __launch_bounds__(256) void gemm_inproj(
    const float* __restrict__ A,
    const float* __restrict__ Wq, const float* __restrict__ Wz,
    const float* __restrict__ Wa, const float* __restrict__ Wb,
    unsigned short* __restrict__ qkv, unsigned short* __restrict__ z,
    float* __restrict__ a_out, float* __restrict__ b_out)
{
    __shared__ float As[16][68];
    __shared__ float Ws[16][68];

    const int t    = threadIdx.x;
    const int row0 = blockIdx.y * 64;
    const int col0 = blockIdx.x * 64;
    const int lm   = t >> 2;
    const int lk   = (t & 3) * 4;
    const int tx   = t & 15, ty = t >> 4;

    float acc[4][4] = {};

    const float* aP = A + (size_t)(row0 + lm) * DIM + lk;
    const float* wP = w_row_multi(col0 + lm, Wq, Wz, Wa, Wb) + lk;

    for (int k0 = 0; k0 < DIM; k0 += 16) {
        float4 av = *(const float4*)(aP + k0);
        float4 wv = *(const float4*)(wP + k0);
        As[lk + 0][lm] = av.x; As[lk + 1][lm] = av.y;
        As[lk + 2][lm] = av.z; As[lk + 3][lm] = av.w;
        Ws[lk + 0][lm] = wv.x; Ws[lk + 1][lm] = wv.y;
        Ws[lk + 2][lm] = wv.z; Ws[lk + 3][lm] = wv.w;
        __syncthreads();
#pragma unroll
        for (int kk = 0; kk < 16; ++kk) {
            float4 a4 = *(const float4*)&As[kk][ty * 4];
            float4 b4 = *(const float4*)&Ws[kk][tx * 4];
            float aa[4] = {a4.x, a4.y, a4.z, a4.w};
            float bb[4] = {b4.x, b4.y, b4.z, b4.w};
#pragma unroll
            for (int i = 0; i < 4; ++i)
#pragma unroll
                for (int j = 0; j < 4; ++j)
                    acc[i][j] += aa[i] * bb[j];
        }
        __syncthreads();
    }

#pragma unroll
    for (int i = 0; i < 4; ++i) {
        int m = row0 + ty * 4 + i;
        int n = col0 + tx * 4;
        store_multi(m, n, make_float4(acc[i][0], acc[i][1], acc[i][2], acc[i][3]),
                    qkv, z, a_out, b_out);
    }
}

// ---------------- out-projection GEMM: out = y(bf16) @ W_out^T ----------------
__global__ __launch_bounds__(256) void gemm_outproj(
    const unsigned short* __restrict__ A,   // (ROWS, VAL_DIM) bf16
    const float* __restrict__ W,            // (DIM, VAL_DIM) f32
    float* __restrict__ C)                  // (ROWS, DIM) f32
{
    __shared__ float As[16][68];
    __shared__ float Ws[16][68];

    const int t    = threadIdx.x;
    const int row0 = blockIdx.y * 64;
    const int col0 = blockIdx.x * 64;
    const int lm   = t >> 2;
    const int lk   = (t & 3) * 4;
    const int tx   = t & 15, ty = t >> 4;

    float acc[4][4] = {};

    const unsigned short* aP = A + (size_t)(row0 + lm) * VAL_DIM + lk;
    const float* wP = W + (size_t)(col0 + lm) * VAL_DIM + lk;

    for (int k0 = 0; k0 < VAL_DIM; k0 += 16) {
        ushort4 au = *(const ushort4*)(aP + k0);
        float4 wv = *(const float4*)(wP + k0);
        As[lk + 0][lm] = bf2f(au.x); As[lk + 1][lm] = bf2f(au.y);
        As[lk + 2][lm] = bf2f(au.z); As[lk + 3][lm] = bf2f(au.w);
        Ws[lk + 0][lm] = wv.x; Ws[lk + 1][lm] = wv.y;
        Ws[lk + 2][lm] = wv.z; Ws[lk + 3][lm] = wv.w;
        __syncthreads();
#pragma unroll
        for (int kk = 0; kk < 16; ++kk) {
            float4 a4 = *(const float4*)&As[kk][ty * 4];
            float4 b4 = *(const float4*)&Ws[kk][tx * 4];
            float aa[4] = {a4.x, a4.y, a4.z, a4.w};
            float bb[4] = {b4.x, b4.y, b4.z, b4.w};
#pragma unroll
            for (int i = 0; i < 4; ++i)
#pragma unroll
                for (int j = 0; j < 4; ++j)
                    acc[i][j] += aa[i] * bb[j];
        }
        __syncthreads();
    }

#pragma unroll
    for (int i = 0; i < 4; ++i) {
        int m = row0 + ty * 4 + i;
        int n = col0 + tx * 4;
        *(float4*)(C + (size_t)m * DIM + n) =
            make_float4(acc[i][0], acc[i][1], acc[i][2], acc[i][3]);
    }
}

// ---------------- depthwise causal conv1d + SiLU (in place, bf16) ----------------
__global__ __launch_bounds__(256) void conv_silu(unsigned short* __restrict__ qkv,
                                                 const float* __restrict__ conv_w)
{
    int idx = blockIdx.x * blockDim.x + threadIdx.x;   // 0..B*CONV_DIM-1
    int b = idx >> 13;
    int c = idx & (CONV_DIM - 1);
    const float w0 = conv_w[c * 4 + 0];
    const float w1 = conv_w[c * 4 + 1];
    const float w2 = conv_w[c * 4 + 2];
    const float w3 = conv_w[c * 4 + 3];
    unsigned short* p = qkv + (size_t)b * L * CONV_DIM + c;
    float x0 = 0.f, x1 = 0.f, x2 = 0.f;
    for (int l0 = 0; l0 < L; l0 += 8) {
        float xv[8];
#pragma unroll
        for (int j = 0; j < 8; ++j) xv[j] = bf2f(p[(size_t)(l0 + j) * CONV_DIM]);
#pragma unroll
        for (int j = 0; j < 8; ++j) {
            float h = w0 * x0 + w1 * x1 + w2 * x2 + w3 * xv[j];
            float s = h / (1.f + __expf(-h));
            p[(size_t)(l0 + j) * CONV_DIM] = f2bf(s);
            x0 = x1; x1 = x2; x2 = xv[j];
        }
    }
}

// ---------------- l2norm of q,k heads (in place, bf16) ----------------
__global__ __launch_bounds__(256) void normqk(unsigned short* __restrict__ qkv)
{
    int wid  = blockIdx.x * 4 + (threadIdx.x >> 6);  // 0..B*L*2*HK-1
    int lane = threadIdx.x & 63;
    int hk  = wid & 15;
    int sel = (wid >> 4) & 1;     // 0 = q, 1 = k
    int row = wid >> 5;           // b*L + l
    unsigned short* p = qkv + (size_t)row * CONV_DIM + sel * KEY_DIM + hk * DK;
    float x0 = bf2f(p[lane]), x1 = bf2f(p[lane + 64]);
    float ss = x0 * x0 + x1 * x1;
#pragma unroll
    for (int o = 32; o >= 1; o >>= 1) ss += __shfl_xor(ss, o);
    float sc = rsqrtf(ss + 1e-6f);
    if (sel == 0) sc *= 0.08838834764831845f;   // DK^-0.5
    p[lane]      = f2bf(x0 * sc);
    p[lane + 64] = f2bf(x1 * sc);
}

// ---------------- gate coefficients: eg = exp(g), beta ----------------
__global__ __launch_bounds__(256) void gatecoef(const float* __restrict__ a_buf,
                                                const float* __restrict__ b_buf,
                                                const float* __restrict__ A_log,
                                                const float* __restrict__ dt_bias,
                                                float* __restrict__ eg,
                                                float* __restrict__ beta)
{
    int idx = blockIdx.x * blockDim.x + threadIdx.x;   // 0..B*L*HV-1
    int h = idx & (HV - 1);
    float av = a_buf[idx];
    float bv = b_buf[idx];
    float x  = av + dt_bias[h];
    float sp = (x > 20.f) ? x : log1pf(__expf(x));     // softplus
    float g  = -__expf(A_log[h]) * sp;
    eg[idx]   = __expf(g);
    beta[idx] = 1.f / (1.f + __expf(-bv));
}

// ---------------- gated delta rule scan + fused gated RMSNorm ----------------
// One block per (b,h); thread tid owns state column v=tid (128 f32 in regs).
// Writes gated-normalized y IN PLACE over z.
__global__ __launch_bounds__(128) void scan_kernel(const unsigned short* __restrict__ qkv,
                                                   const float* __restrict__ eg_buf,
                                                   const float* __restrict__ beta_buf,
                                                   unsigned short* __restrict__ z_io,
                                                   const float* __restrict__ nw)
{
    int b  = blockIdx.x >> 5;
    int h  = blockIdx.x & (HV - 1);
    int hk = h >> 1;                    // rep = HV/HK = 2
    int tid  = threadIdx.x;
    int lane = tid & 63;
    int wv   = tid >> 6;

    __shared__ __align__(16) float ks[DK];
    __shared__ __align__(16) float qs[DK];
    __shared__ float wsum[2];

    float state[DK];
#pragma unroll
    for (int i = 0; i < DK; ++i) state[i] = 0.f;

    const float nw_t = nw[tid];
    const unsigned short* base = qkv + (size_t)b * L * CONV_DIM;

    // prefetch row 0
    float qn = bf2f(base[hk * DK + tid]);
    float kn = bf2f(base[KEY_DIM + hk * DK + tid]);
    float vn = bf2f(base[2 * KEY_DIM + h * DV + tid]);

    for (int l = 0; l < L; ++l) {
        qs[tid] = qn;
        ks[tid] = kn;
        float vt = vn;
        int gi = (b * L + l) * HV + h;
        float egt = eg_buf[gi];
        float bt  = beta_buf[gi];
        size_t zi = (size_t)(b * L + l) * VAL_DIM + h * DV + tid;
        float zv = bf2f(z_io[zi]);
        __syncthreads();

        if (l + 1 < L) {   // prefetch next row while computing
            const unsigned short* nrow = base + (size_t)(l + 1) * CONV_DIM;
            qn = bf2f(nrow[hk * DK + tid]);
            kn = bf2f(nrow[KEY_DIM + hk * DK + tid]);
            vn = bf2f(nrow[2 * KEY_DIM + h * DV + tid]);
        }

        const float4* k4 = (const float4*)ks;
        const float4* q4 = (const float4*)qs;

        float d0 = 0.f, d1 = 0.f, d2 = 0.f, d3 = 0.f;
#pragma unroll
        for (int kc = 0; kc < DK / 4; ++kc) {
            float4 kk = k4[kc];
            d0 += kk.x * state[4 * kc + 0];
            d1 += kk.y * state[4 * kc + 1];
            d2 += kk.z * state[4 * kc + 2];
            d3 += kk.w * state[4 * kc + 3];
        }
        float kvmem = ((d0 + d1) + (d2 + d3)) * egt;
        float delta = (vt - kvmem) * bt;

        float o0 = 0.f, o1 = 0.f, o2 = 0.f, o3 = 0.f;
#pragma unroll
        for (int kc = 0; kc < DK / 4; ++kc) {
            float4 kk = k4[kc];
            float4 qq = q4[kc];
            float s0 = egt * state[4 * kc + 0] + delta * kk.x; state[4 * kc + 0] = s0; o0 += qq.x * s0;
            float s1 = egt * state[4 * kc + 1] + delta * kk.y; state[4 * kc + 1] = s1; o1 += qq.y * s1;
            float s2 = egt * state[4 * kc + 2] + delta * kk.z; state[4 * kc + 2] = s2; o2 += qq.z * s2;
            float s3 = egt * state[4 * kc + 3] + delta * kk.w; state[4 * kc + 3] = s3; o3 += qq.w * s3;
        }
        float o = (o0 + o1) + (o2 + o3);

        // fused gated RMSNorm over DV (block-wide reduction of o^2)
        float ss = o * o;
#pragma unroll
        for (int off = 32; off >= 1; off >>= 1) ss += __shfl_xor(ss, off);
        if (lane == 0) wsum[wv] = ss;
        __syncthreads();
        float inv = rsqrtf((wsum[0] + wsum[1]) * (1.f / DV) + EPS);
        float yv = o * inv * nw_t * (zv / (1.f + __expf(-zv)));
        z_io[zi] = f2bf(yv);
    }
}

// ---------------- launch ----------------
extern "C" void kernel_launch(void* const* d_in, const int* in_sizes, int n_in,
                              void* d_out, int out_size, void* d_ws, size_t ws_size,
                              hipStream_t stream)
{
    const float* x        = (const float*)d_in[0];
    const float* W_qkv    = (const float*)d_in[1];
    const float* W_z      = (const float*)d_in[2];
    const float* W_a      = (const float*)d_in[3];
    const float* W_b      = (const float*)d_in[4];
    const float* conv_w   = (const float*)d_in[5];
    const float* A_log    = (const float*)d_in[6];
    const float* dt_bias  = (const float*)d_in[7];
    const float* norm_w   = (const float*)d_in[8];
    const float* W_out    = (const float*)d_in[9];
    float* out = (float*)d_out;
    char*  ws  = (char*)d_ws;

    if (ws_size < WS_NEED_BYTES) return;  // refuse to corrupt memory

    unsigned short* qkv  = (unsigned short*)(ws + OFF_QKV);
    unsigned short* z    = (unsigned short*)(ws + OFF_Z);
    float* a    = (float*)(ws + OFF_A);
    float* bb   = (float*)(ws + OFF_B);
    float* eg   = (float*)(ws + OFF_EG);
    float* beta = (float*)(ws + OFF_BETA);

    // 1. fused input projections: (4096 x 12352 x 2048)
    dim3 g1(NPROJ / 64, ROWS / 64);
    gemm_inproj<<<g1, 256, 0, stream>>>(x, W_qkv, W_z, W_a, W_b, qkv, z, a, bb);
    // 2. depthwise causal conv + silu (in place)
    conv_silu<<<(B * CONV_DIM) / 256, 256, 0, stream>>>(qkv, conv_w);
    // 3. l2norm q,k heads (in place)
    normqk<<<(B * L * 2 * HK) / 4, 256, 0, stream>>>(qkv);
    // 4. gate coefficients
    gatecoef<<<(B * L * HV) / 256, 256, 0, stream>>>(a, bb, A_log, dt_bias, eg, beta);
    // 5. gated delta rule scan + fused gated RMSNorm (y overwrites z)
    scan_kernel<<<B * HV, 128, 0, stream>>>(qkv, eg, beta, z, norm_w);
    // 6. output projection: (4096 x 2048 x 4096), A = y (bf16)
    dim3 g2(DIM / 64, ROWS / 64);
    gemm_outproj<<<g2, 256, 0, stream>>>(z, W_out, out);
}

// Round 3
// 5092.817 us; speedup vs baseline: 1.8499x; 1.8499x over previous
//
#include <hip/hip_runtime.h>
#include <hip/hip_bf16.h>
#include <cstddef>
#include <cstdint>

// ---------------- problem constants ----------------
constexpr int B = 2, L = 2048, DIM = 2048;
constexpr int HK = 16, HV = 32, DK = 128, DV = 128;
constexpr int KEY_DIM = HK * DK;                    // 2048
constexpr int VAL_DIM = HV * DV;                    // 4096
constexpr int CONV_DIM = 2 * KEY_DIM + VAL_DIM;     // 8192
constexpr int NPROJ = CONV_DIM + VAL_DIM + HV + HV; // 12352
constexpr size_t ROWS = (size_t)B * L;              // 4096
constexpr float EPS = 1e-6f;

// workspace layout (BYTE offsets). Total ~98 MB.
constexpr size_t OFF_QKV  = 0;                                   // bf16
constexpr size_t OFF_Z    = OFF_QKV + ROWS * CONV_DIM * 2;       // bf16 (y in-place)
constexpr size_t OFF_A    = OFF_Z   + ROWS * VAL_DIM * 2;        // f32
constexpr size_t OFF_B    = OFF_A   + ROWS * HV * 4;
constexpr size_t OFF_EG   = OFF_B   + ROWS * HV * 4;
constexpr size_t OFF_BETA = OFF_EG  + ROWS * HV * 4;
constexpr size_t WS_NEED_BYTES = OFF_BETA + ROWS * HV * 4;       // ~103 MB

// ---------------- bf16 helpers ----------------
__device__ __forceinline__ float bf2f(unsigned short u) {
    union { float f; uint32_t i; } c; c.i = ((uint32_t)u) << 16; return c.f;
}
__device__ __forceinline__ unsigned short f2bf(float f) {
    union { float f; uint32_t u; } c; c.f = f;
    uint32_t u = c.u + 0x7FFFu + ((c.u >> 16) & 1u);   // RTNE
    return (unsigned short)(u >> 16);
}
__device__ __forceinline__ uint32_t pk2(float a, float b) {
    return (uint32_t)f2bf(a) | ((uint32_t)f2bf(b) << 16);
}

// MFMA fragment types (16x16x32 bf16)
typedef __attribute__((ext_vector_type(8))) short bfrag;   // 8 bf16 = 4 VGPRs
typedef __attribute__((ext_vector_type(4))) float ffrag;   // 4 f32 acc

// LDS tile: 128 rows x 32 k-elems, stride 40 bf16 (80 B, 16B-multiple)
constexpr int SA = 40;

// ---------------- in-projection MFMA GEMM ----------------
__device__ __forceinline__ const float* w_row_multi(int n, const float* Wq, const float* Wz,
                                                    const float* Wa, const float* Wb) {
    if (n < CONV_DIM)                return Wq + (size_t)n * DIM;
    if (n < CONV_DIM + VAL_DIM)      return Wz + (size_t)(n - CONV_DIM) * DIM;
    if (n < CONV_DIM + VAL_DIM + HV) return Wa + (size_t)(n - CONV_DIM - VAL_DIM) * DIM;
    return Wb + (size_t)(n - CONV_DIM - VAL_DIM - HV) * DIM;
}

__device__ __forceinline__ void store_multi(int m, int n, float v,
                                            unsigned short* qkv, unsigned short* z,
                                            float* a, float* b) {
    if (n < CONV_DIM) {
        qkv[(size_t)m * CONV_DIM + n] = f2bf(v);
    } else if (n < CONV_DIM + VAL_DIM) {
        z[(size_t)m * VAL_DIM + (n - CONV_DIM)] = f2bf(v);
    } else if (n < CONV_DIM + VAL_DIM + HV) {
        a[(size_t)m * HV + (n - CONV_DIM - VAL_DIM)] = v;
    } else if (n < NPROJ) {
        b[(size_t)m * HV + (n - CONV_DIM - VAL_DIM - HV)] = v;
    }
}

__global__ __launch_bounds__(256) void gemm_inproj(
    const float* __restrict__ x,
    const float* __restrict__ Wq, const float* __restrict__ Wz,
    const float* __restrict__ Wa, const float* __restrict__ Wb,
    unsigned short* __restrict__ qkv, unsigned short* __restrict__ z,
    float* __restrict__ a_out, float* __restrict__ b_out)
{
    __shared__ __align__(16) unsigned short As[128 * SA];
    __shared__ __align__(16) unsigned short Ws[128 * SA];

    const int t    = threadIdx.x;
    const int row0 = blockIdx.y * 128;
    const int col0 = blockIdx.x * 128;
    const int r    = t >> 1;            // 0..127
    const int kh   = (t & 1) * 16;      // 0 or 16
    const int lane = t & 63;
    const int wid  = t >> 6;
    const int wm   = (wid >> 1) * 64;   // wave row offset in tile
    const int wn   = (wid & 1) * 64;    // wave col offset
    const int quad = lane >> 4;
    const int l16  = lane & 15;

    ffrag acc[4][4];
#pragma unroll
    for (int i = 0; i < 4; ++i)
#pragma unroll
        for (int j = 0; j < 4; ++j) acc[i][j] = (ffrag)0.f;

    const float* aP = x + (size_t)(row0 + r) * DIM + kh;
    const int wr = col0 + r;
    const float* wP = ((wr < NPROJ) ? w_row_multi(wr, Wq, Wz, Wa, Wb) : Wq) + kh;

    const int aoff = r * SA + kh;
    const int fa   = (wm + l16) * SA + quad * 8;
    const int fb   = (wn + l16) * SA + quad * 8;

    for (int k0 = 0; k0 < DIM; k0 += 32) {
        float4 av0 = *(const float4*)(aP + k0);
        float4 av1 = *(const float4*)(aP + k0 + 4);
        float4 av2 = *(const float4*)(aP + k0 + 8);
        float4 av3 = *(const float4*)(aP + k0 + 12);
        float4 wv0 = *(const float4*)(wP + k0);
        float4 wv1 = *(const float4*)(wP + k0 + 4);
        float4 wv2 = *(const float4*)(wP + k0 + 8);
        float4 wv3 = *(const float4*)(wP + k0 + 12);
        __syncthreads();
        *(uint4*)&As[aoff]     = make_uint4(pk2(av0.x, av0.y), pk2(av0.z, av0.w),
                                            pk2(av1.x, av1.y), pk2(av1.z, av1.w));
        *(uint4*)&As[aoff + 8] = make_uint4(pk2(av2.x, av2.y), pk2(av2.z, av2.w),
                                            pk2(av3.x, av3.y), pk2(av3.z, av3.w));
        *(uint4*)&Ws[aoff]     = make_uint4(pk2(wv0.x, wv0.y), pk2(wv0.z, wv0.w),
                                            pk2(wv1.x, wv1.y), pk2(wv1.z, wv1.w));
        *(uint4*)&Ws[aoff + 8] = make_uint4(pk2(wv2.x, wv2.y), pk2(wv2.z, wv2.w),
                                            pk2(wv3.x, wv3.y), pk2(wv3.z, wv3.w));
        __syncthreads();

        bfrag aF[4], bF[4];
#pragma unroll
        for (int mt = 0; mt < 4; ++mt) aF[mt] = *(const bfrag*)&As[fa + mt * 16 * SA];
#pragma unroll
        for (int nt = 0; nt < 4; ++nt) bF[nt] = *(const bfrag*)&Ws[fb + nt * 16 * SA];
#pragma unroll
        for (int mt = 0; mt < 4; ++mt)
#pragma unroll
            for (int nt = 0; nt < 4; ++nt)
                acc[mt][nt] = __builtin_amdgcn_mfma_f32_16x16x32_bf16(
                    aF[mt], bF[nt], acc[mt][nt], 0, 0, 0);
    }

#pragma unroll
    for (int mt = 0; mt < 4; ++mt)
#pragma unroll
        for (int nt = 0; nt < 4; ++nt) {
            int gr = row0 + wm + mt * 16 + quad * 4;
            int gc = col0 + wn + nt * 16 + l16;
#pragma unroll
            for (int reg = 0; reg < 4; ++reg)
                store_multi(gr + reg, gc, acc[mt][nt][reg], qkv, z, a_out, b_out);
        }
}

// ---------------- out-projection MFMA GEMM: out = y(bf16) @ W_out^T ----------------
__global__ __launch_bounds__(256) void gemm_outproj(
    const unsigned short* __restrict__ A,   // (ROWS, VAL_DIM) bf16
    const float* __restrict__ W,            // (DIM, VAL_DIM) f32
    float* __restrict__ C)                  // (ROWS, DIM) f32
{
    __shared__ __align__(16) unsigned short As[128 * SA];
    __shared__ __align__(16) unsigned short Ws[128 * SA];

    const int t    = threadIdx.x;
    const int row0 = blockIdx.y * 128;
    const int col0 = blockIdx.x * 128;
    const int r    = t >> 1;
    const int kh   = (t & 1) * 16;
    const int lane = t & 63;
    const int wid  = t >> 6;
    const int wm   = (wid >> 1) * 64;
    const int wn   = (wid & 1) * 64;
    const int quad = lane >> 4;
    const int l16  = lane & 15;

    ffrag acc[4][4];
#pragma unroll
    for (int i = 0; i < 4; ++i)
#pragma unroll
        for (int j = 0; j < 4; ++j) acc[i][j] = (ffrag)0.f;

    const unsigned short* aP = A + (size_t)(row0 + r) * VAL_DIM + kh;
    const float* wP = W + (size_t)(col0 + r) * VAL_DIM + kh;

    const int aoff = r * SA + kh;
    const int fa   = (wm + l16) * SA + quad * 8;
    const int fb   = (wn + l16) * SA + quad * 8;

    for (int k0 = 0; k0 < VAL_DIM; k0 += 32) {
        uint4 au0 = *(const uint4*)(aP + k0);       // 8 bf16
        uint4 au1 = *(const uint4*)(aP + k0 + 8);
        float4 wv0 = *(const float4*)(wP + k0);
        float4 wv1 = *(const float4*)(wP + k0 + 4);
        float4 wv2 = *(const float4*)(wP + k0 + 8);
        float4 wv3 = *(const float4*)(wP + k0 + 12);
        __syncthreads();
        *(uint4*)&As[aoff]     = au0;
        *(uint4*)&As[aoff + 8] = au1;
        *(uint4*)&Ws[aoff]     = make_uint4(pk2(wv0.x, wv0.y), pk2(wv0.z, wv0.w),
                                            pk2(wv1.x, wv1.y), pk2(wv1.z, wv1.w));
        *(uint4*)&Ws[aoff + 8] = make_uint4(pk2(wv2.x, wv2.y), pk2(wv2.z, wv2.w),
                                            pk2(wv3.x, wv3.y), pk2(wv3.z, wv3.w));
        __syncthreads();

        bfrag aF[4], bF[4];
#pragma unroll
        for (int mt = 0; mt < 4; ++mt) aF[mt] = *(const bfrag*)&As[fa + mt * 16 * SA];
#pragma unroll
        for (int nt = 0; nt < 4; ++nt) bF[nt] = *(const bfrag*)&Ws[fb + nt * 16 * SA];
#pragma unroll
        for (int mt = 0; mt < 4; ++mt)
#pragma unroll
            for (int nt = 0; nt < 4; ++nt)
                acc[mt][nt] = __builtin_amdgcn_mfma_f32_16x16x32_bf16(
                    aF[mt], bF[nt], acc[mt][nt], 0, 0, 0);
    }

#pragma unroll
    for (int mt = 0; mt < 4; ++mt)
#pragma unroll
        for (int nt = 0; nt < 4; ++nt) {
            int gr = row0 + wm + mt * 16 + quad * 4;
            int gc = col0 + wn + nt * 16 + l16;
#pragma unroll
            for (int reg = 0; reg < 4; ++reg)
                C[(size_t)(gr + reg) * DIM + gc] = acc[mt][nt][reg];
        }
}

// ---------------- depthwise causal conv1d + SiLU (in place, bf16) ----------------
__global__ __launch_bounds__(256) void conv_silu(unsigned short* __restrict__ qkv,
                                                 const float* __restrict__ conv_w)
{
    int idx = blockIdx.x * blockDim.x + threadIdx.x;
    int b = idx >> 13;
    int c = idx & (CONV_DIM - 1);
    const float w0 = conv_w[c * 4 + 0];
    const float w1 = conv_w[c * 4 + 1];
    const float w2 = conv_w[c * 4 + 2];
    const float w3 = conv_w[c * 4 + 3];
    unsigned short* p = qkv + (size_t)b * L * CONV_DIM + c;
    float x0 = 0.f, x1 = 0.f, x2 = 0.f;
    for (int l0 = 0; l0 < L; l0 += 8) {
        float xv[8];
#pragma unroll
        for (int j = 0; j < 8; ++j) xv[j] = bf2f(p[(size_t)(l0 + j) * CONV_DIM]);
#pragma unroll
        for (int j = 0; j < 8; ++j) {
            float h = w0 * x0 + w1 * x1 + w2 * x2 + w3 * xv[j];
            float s = h / (1.f + __expf(-h));
            p[(size_t)(l0 + j) * CONV_DIM] = f2bf(s);
            x0 = x1; x1 = x2; x2 = xv[j];
        }
    }
}

// ---------------- l2norm of q,k heads (in place, bf16) ----------------
__global__ __launch_bounds__(256) void normqk(unsigned short* __restrict__ qkv)
{
    int wid  = blockIdx.x * 4 + (threadIdx.x >> 6);
    int lane = threadIdx.x & 63;
    int hk  = wid & 15;
    int sel = (wid >> 4) & 1;
    int row = wid >> 5;
    unsigned short* p = qkv + (size_t)row * CONV_DIM + sel * KEY_DIM + hk * DK;
    float x0 = bf2f(p[lane]), x1 = bf2f(p[lane + 64]);
    float ss = x0 * x0 + x1 * x1;
#pragma unroll
    for (int o = 32; o >= 1; o >>= 1) ss += __shfl_xor(ss, o);
    float sc = rsqrtf(ss + 1e-6f);
    if (sel == 0) sc *= 0.08838834764831845f;   // DK^-0.5
    p[lane]      = f2bf(x0 * sc);
    p[lane + 64] = f2bf(x1 * sc);
}

// ---------------- gate coefficients ----------------
__global__ __launch_bounds__(256) void gatecoef(const float* __restrict__ a_buf,
                                                const float* __restrict__ b_buf,
                                                const float* __restrict__ A_log,
                                                const float* __restrict__ dt_bias,
                                                float* __restrict__ eg,
                                                float* __restrict__ beta)
{
    int idx = blockIdx.x * blockDim.x + threadIdx.x;
    int h = idx & (HV - 1);
    float av = a_buf[idx];
    float bv = b_buf[idx];
    float x  = av + dt_bias[h];
    float sp = (x > 20.f) ? x : log1pf(__expf(x));
    float g  = -__expf(A_log[h]) * sp;
    eg[idx]   = __expf(g);
    beta[idx] = 1.f / (1.f + __expf(-bv));
}

// ---------------- gated delta rule scan — barrier-free, one wave per task ----
// grid = B*HV*2 blocks of 64 threads. Task = (b, h, 64-col slab of DV).
// Thread owns one full state column (128 f32 regs). o overwrites v slice (bf16).
__global__ __launch_bounds__(64) void scan_kernel(unsigned short* __restrict__ qkv,
                                                  const float* __restrict__ eg_buf,
                                                  const float* __restrict__ beta_buf)
{
    const int blk  = blockIdx.x;
    const int b    = blk >> 6;
    const int h    = (blk >> 1) & (HV - 1);
    const int slab = blk & 1;
    const int lane = threadIdx.x;
    const int col  = slab * 64 + lane;
    const int hk   = h >> 1;

    __shared__ __align__(16) float ks[DK];
    __shared__ __align__(16) float qs[DK];

    float state[DK];
#pragma unroll
    for (int i = 0; i < DK; ++i) state[i] = 0.f;

    unsigned short* base = qkv + (size_t)b * L * CONV_DIM;
    const int qoff = hk * DK + 2 * lane;
    const int koff = KEY_DIM + hk * DK + 2 * lane;
    const int voff = 2 * KEY_DIM + h * DV + col;

    // prefetch step 0
    uint32_t kr = *(const uint32_t*)(base + koff);
    uint32_t qr = *(const uint32_t*)(base + qoff);
    unsigned short vr = base[voff];
    float egn = eg_buf[(size_t)b * L * HV + h];
    float btn = beta_buf[(size_t)b * L * HV + h];

    for (int l = 0; l < L; ++l) {
        ks[2 * lane]     = bf2f((unsigned short)(kr & 0xffffu));
        ks[2 * lane + 1] = bf2f((unsigned short)(kr >> 16));
        qs[2 * lane]     = bf2f((unsigned short)(qr & 0xffffu));
        qs[2 * lane + 1] = bf2f((unsigned short)(qr >> 16));
        float vt = bf2f(vr);
        float egt = egn, bt = btn;
        unsigned short* optr = base + (size_t)l * CONV_DIM + voff;

        if (l + 1 < L) {   // prefetch next step
            unsigned short* nrow = base + (size_t)(l + 1) * CONV_DIM;
            kr = *(const uint32_t*)(nrow + koff);
            qr = *(const uint32_t*)(nrow + qoff);
            vr = nrow[voff];
            size_t gi = ((size_t)b * L + l + 1) * HV + h;
            egn = eg_buf[gi];
            btn = beta_buf[gi];
        }

        const float4* k4 = (const float4*)ks;
        const float4* q4 = (const float4*)qs;

        // kvmem = sum_i k[i] * state[i]  (8 independent chains)
        float a0 = 0.f, a1 = 0.f, a2 = 0.f, a3 = 0.f;
        float a4 = 0.f, a5 = 0.f, a6 = 0.f, a7 = 0.f;
#pragma unroll
        for (int kc = 0; kc < 16; ++kc) {
            float4 kA = k4[2 * kc], kB = k4[2 * kc + 1];
            a0 += kA.x * state[8 * kc + 0];
            a1 += kA.y * state[8 * kc + 1];
            a2 += kA.z * state[8 * kc + 2];
            a3 += kA.w * state[8 * kc + 3];
            a4 += kB.x * state[8 * kc + 4];
            a5 += kB.y * state[8 * kc + 5];
            a6 += kB.z * state[8 * kc + 6];
            a7 += kB.w * state[8 * kc + 7];
        }
        float kvmem = (((a0 + a1) + (a2 + a3)) + ((a4 + a5) + (a6 + a7))) * egt;
        float delta = (vt - kvmem) * bt;

        // state = egt*state + delta*k;  o = sum_i q[i]*state[i]
        float o0 = 0.f, o1 = 0.f, o2 = 0.f, o3 = 0.f;
        float o4 = 0.f, o5 = 0.f, o6 = 0.f, o7 = 0.f;
#pragma unroll
        for (int kc = 0; kc < 16; ++kc) {
            float4 kA = k4[2 * kc], kB = k4[2 * kc + 1];
            float4 qA = q4[2 * kc], qB = q4[2 * kc + 1];
            float s0 = egt * state[8 * kc + 0] + delta * kA.x; state[8 * kc + 0] = s0; o0 += qA.x * s0;
            float s1 = egt * state[8 * kc + 1] + delta * kA.y; state[8 * kc + 1] = s1; o1 += qA.y * s1;
            float s2 = egt * state[8 * kc + 2] + delta * kA.z; state[8 * kc + 2] = s2; o2 += qA.z * s2;
            float s3 = egt * state[8 * kc + 3] + delta * kA.w; state[8 * kc + 3] = s3; o3 += qA.w * s3;
            float s4 = egt * state[8 * kc + 4] + delta * kB.x; state[8 * kc + 4] = s4; o4 += qB.x * s4;
            float s5 = egt * state[8 * kc + 5] + delta * kB.y; state[8 * kc + 5] = s5; o5 += qB.y * s5;
            float s6 = egt * state[8 * kc + 6] + delta * kB.z; state[8 * kc + 6] = s6; o6 += qB.z * s6;
            float s7 = egt * state[8 * kc + 7] + delta * kB.w; state[8 * kc + 7] = s7; o7 += qB.w * s7;
        }
        float o = (((o0 + o1) + (o2 + o3)) + ((o4 + o5) + (o6 + o7)));
        *optr = f2bf(o);
    }
}

// ---------------- gated RMSNorm: y = norm(o)*w*silu(z), y overwrites z ------
__global__ __launch_bounds__(256) void gate_norm(const unsigned short* __restrict__ qkv,
                                                 unsigned short* __restrict__ z_io,
                                                 const float* __restrict__ nw)
{
    int wid  = blockIdx.x * 4 + (threadIdx.x >> 6);   // 0..B*L*HV-1
    int lane = threadIdx.x & 63;
    int h   = wid & (HV - 1);
    int row = wid >> 5;
    const unsigned short* op = qkv + (size_t)row * CONV_DIM + 2 * KEY_DIM + h * DV;
    float x0 = bf2f(op[lane]), x1 = bf2f(op[lane + 64]);
    float ss = x0 * x0 + x1 * x1;
#pragma unroll
    for (int o = 32; o >= 1; o >>= 1) ss += __shfl_xor(ss, o);
    float inv = rsqrtf(ss * (1.f / DV) + EPS);
    unsigned short* zp = z_io + (size_t)row * VAL_DIM + h * DV;
    float z0 = bf2f(zp[lane]), z1 = bf2f(zp[lane + 64]);
    float y0 = x0 * inv * nw[lane]      * (z0 / (1.f + __expf(-z0)));
    float y1 = x1 * inv * nw[lane + 64] * (z1 / (1.f + __expf(-z1)));
    zp[lane]      = f2bf(y0);
    zp[lane + 64] = f2bf(y1);
}

// ---------------- launch ----------------
extern "C" void kernel_launch(void* const* d_in, const int* in_sizes, int n_in,
                              void* d_out, int out_size, void* d_ws, size_t ws_size,
                              hipStream_t stream)
{
    const float* x        = (const float*)d_in[0];
    const float* W_qkv    = (const float*)d_in[1];
    const float* W_z      = (const float*)d_in[2];
    const float* W_a      = (const float*)d_in[3];
    const float* W_b      = (const float*)d_in[4];
    const float* conv_w   = (const float*)d_in[5];
    const float* A_log    = (const float*)d_in[6];
    const float* dt_bias  = (const float*)d_in[7];
    const float* norm_w   = (const float*)d_in[8];
    const float* W_out    = (const float*)d_in[9];
    float* out = (float*)d_out;
    char*  ws  = (char*)d_ws;

    if (ws_size < WS_NEED_BYTES) return;

    unsigned short* qkv = (unsigned short*)(ws + OFF_QKV);
    unsigned short* z   = (unsigned short*)(ws + OFF_Z);
    float* a    = (float*)(ws + OFF_A);
    float* bb   = (float*)(ws + OFF_B);
    float* eg   = (float*)(ws + OFF_EG);
    float* beta = (float*)(ws + OFF_BETA);

    // 1. fused input projections (MFMA bf16): (4096 x 12352 x 2048)
    dim3 g1((NPROJ + 127) / 128, ROWS / 128);
    gemm_inproj<<<g1, 256, 0, stream>>>(x, W_qkv, W_z, W_a, W_b, qkv, z, a, bb);
    // 2. depthwise causal conv + silu (in place)
    conv_silu<<<(B * CONV_DIM) / 256, 256, 0, stream>>>(qkv, conv_w);
    // 3. l2norm q,k heads (in place)
    normqk<<<(B * L * 2 * HK) / 4, 256, 0, stream>>>(qkv);
    // 4. gate coefficients
    gatecoef<<<(B * L * HV) / 256, 256, 0, stream>>>(a, bb, A_log, dt_bias, eg, beta);
    // 5. gated delta rule scan (barrier-free; o overwrites v slice of qkv)
    scan_kernel<<<B * HV * 2, 64, 0, stream>>>(qkv, eg, beta);
    // 6. gated RMSNorm + silu(z) (y overwrites z)
    gate_norm<<<(B * L * HV) / 4, 256, 0, stream>>>(qkv, z, norm_w);
    // 7. output projection (MFMA bf16): (4096 x 2048 x 4096)
    dim3 g2(DIM / 128, ROWS / 128);
    gemm_outproj<<<g2, 256, 0, stream>>>(z, W_out, out);
}

// Round 4
// 1881.646 us; speedup vs baseline: 5.0069x; 2.7066x over previous
//
#include <hip/hip_runtime.h>
#include <hip/hip_bf16.h>
#include <cstddef>
#include <cstdint>

// ---------------- problem constants ----------------
constexpr int B = 2, L = 2048, DIM = 2048;
constexpr int HK = 16, HV = 32, DK = 128, DV = 128;
constexpr int KEY_DIM = HK * DK;                    // 2048
constexpr int VAL_DIM = HV * DV;                    // 4096
constexpr int CONV_DIM = 2 * KEY_DIM + VAL_DIM;     // 8192
constexpr int NPROJ = CONV_DIM + VAL_DIM + HV + HV; // 12352
constexpr size_t ROWS = (size_t)B * L;              // 4096
constexpr float EPS = 1e-6f;
constexpr int CHUNK = 64, NCHUNK = L / CHUNK;       // 32 chunks

// workspace layout (BYTE offsets). Total ~103 MB.
constexpr size_t OFF_QKV  = 0;                                   // bf16
constexpr size_t OFF_Z    = OFF_QKV + ROWS * CONV_DIM * 2;       // bf16 (y in-place)
constexpr size_t OFF_A    = OFF_Z   + ROWS * VAL_DIM * 2;        // f32
constexpr size_t OFF_B    = OFF_A   + ROWS * HV * 4;
constexpr size_t OFF_G    = OFF_B   + ROWS * HV * 4;             // g (log-space)
constexpr size_t OFF_BETA = OFF_G   + ROWS * HV * 4;
constexpr size_t WS_NEED_BYTES = OFF_BETA + ROWS * HV * 4;

// ---------------- bf16 helpers ----------------
__device__ __forceinline__ float bf2f(unsigned short u) {
    union { float f; uint32_t i; } c; c.i = ((uint32_t)u) << 16; return c.f;
}
__device__ __forceinline__ float lo_bf(uint32_t u) {
    union { float f; uint32_t i; } c; c.i = u << 16; return c.f;
}
__device__ __forceinline__ float hi_bf(uint32_t u) {
    union { float f; uint32_t i; } c; c.i = u & 0xFFFF0000u; return c.f;
}
__device__ __forceinline__ unsigned short f2bf(float f) {
    union { float f; uint32_t u; } c; c.f = f;
    uint32_t u = c.u + 0x7FFFu + ((c.u >> 16) & 1u);   // RTNE
    return (unsigned short)(u >> 16);
}
__device__ __forceinline__ uint32_t pk2(float a, float b) {
    return (uint32_t)f2bf(a) | ((uint32_t)f2bf(b) << 16);
}

// MFMA fragment types (16x16x32 bf16)
typedef __attribute__((ext_vector_type(8))) short bfrag;   // 8 bf16
typedef __attribute__((ext_vector_type(4))) float ffrag;   // 4 f32

constexpr int SA = 40;   // GEMM LDS row stride (bf16)

// ================= in-projection MFMA GEMM =================
__device__ __forceinline__ const float* w_row_multi(int n, const float* Wq, const float* Wz,
                                                    const float* Wa, const float* Wb) {
    if (n < CONV_DIM)                return Wq + (size_t)n * DIM;
    if (n < CONV_DIM + VAL_DIM)      return Wz + (size_t)(n - CONV_DIM) * DIM;
    if (n < CONV_DIM + VAL_DIM + HV) return Wa + (size_t)(n - CONV_DIM - VAL_DIM) * DIM;
    return Wb + (size_t)(n - CONV_DIM - VAL_DIM - HV) * DIM;
}

__device__ __forceinline__ void store_multi(int m, int n, float v,
                                            unsigned short* qkv, unsigned short* z,
                                            float* a, float* b) {
    if (n < CONV_DIM) {
        qkv[(size_t)m * CONV_DIM + n] = f2bf(v);
    } else if (n < CONV_DIM + VAL_DIM) {
        z[(size_t)m * VAL_DIM + (n - CONV_DIM)] = f2bf(v);
    } else if (n < CONV_DIM + VAL_DIM + HV) {
        a[(size_t)m * HV + (n - CONV_DIM - VAL_DIM)] = v;
    } else if (n < NPROJ) {
        b[(size_t)m * HV + (n - CONV_DIM - VAL_DIM - HV)] = v;
    }
}

__global__ __launch_bounds__(256) void gemm_inproj(
    const float* __restrict__ x,
    const float* __restrict__ Wq, const float* __restrict__ Wz,
    const float* __restrict__ Wa, const float* __restrict__ Wb,
    unsigned short* __restrict__ qkv, unsigned short* __restrict__ z,
    float* __restrict__ a_out, float* __restrict__ b_out)
{
    __shared__ __align__(16) unsigned short As[128 * SA];
    __shared__ __align__(16) unsigned short Ws[128 * SA];

    const int t    = threadIdx.x;
    const int row0 = blockIdx.y * 128;
    const int col0 = blockIdx.x * 128;
    const int r    = t >> 1;
    const int kh   = (t & 1) * 16;
    const int lane = t & 63;
    const int wid  = t >> 6;
    const int wm   = (wid >> 1) * 64;
    const int wn   = (wid & 1) * 64;
    const int quad = lane >> 4;
    const int l16  = lane & 15;

    ffrag acc[4][4];
#pragma unroll
    for (int i = 0; i < 4; ++i)
#pragma unroll
        for (int j = 0; j < 4; ++j) acc[i][j] = (ffrag)0.f;

    const float* aP = x + (size_t)(row0 + r) * DIM + kh;
    const int wr = col0 + r;
    const float* wP = ((wr < NPROJ) ? w_row_multi(wr, Wq, Wz, Wa, Wb) : Wq) + kh;

    const int aoff = r * SA + kh;
    const int fa   = (wm + l16) * SA + quad * 8;
    const int fb   = (wn + l16) * SA + quad * 8;

    for (int k0 = 0; k0 < DIM; k0 += 32) {
        float4 av0 = *(const float4*)(aP + k0);
        float4 av1 = *(const float4*)(aP + k0 + 4);
        float4 av2 = *(const float4*)(aP + k0 + 8);
        float4 av3 = *(const float4*)(aP + k0 + 12);
        float4 wv0 = *(const float4*)(wP + k0);
        float4 wv1 = *(const float4*)(wP + k0 + 4);
        float4 wv2 = *(const float4*)(wP + k0 + 8);
        float4 wv3 = *(const float4*)(wP + k0 + 12);
        __syncthreads();
        *(uint4*)&As[aoff]     = make_uint4(pk2(av0.x, av0.y), pk2(av0.z, av0.w),
                                            pk2(av1.x, av1.y), pk2(av1.z, av1.w));
        *(uint4*)&As[aoff + 8] = make_uint4(pk2(av2.x, av2.y), pk2(av2.z, av2.w),
                                            pk2(av3.x, av3.y), pk2(av3.z, av3.w));
        *(uint4*)&Ws[aoff]     = make_uint4(pk2(wv0.x, wv0.y), pk2(wv0.z, wv0.w),
                                            pk2(wv1.x, wv1.y), pk2(wv1.z, wv1.w));
        *(uint4*)&Ws[aoff + 8] = make_uint4(pk2(wv2.x, wv2.y), pk2(wv2.z, wv2.w),
                                            pk2(wv3.x, wv3.y), pk2(wv3.z, wv3.w));
        __syncthreads();

        bfrag aF[4], bF[4];
#pragma unroll
        for (int mt = 0; mt < 4; ++mt) aF[mt] = *(const bfrag*)&As[fa + mt * 16 * SA];
#pragma unroll
        for (int nt = 0; nt < 4; ++nt) bF[nt] = *(const bfrag*)&Ws[fb + nt * 16 * SA];
#pragma unroll
        for (int mt = 0; mt < 4; ++mt)
#pragma unroll
            for (int nt = 0; nt < 4; ++nt)
                acc[mt][nt] = __builtin_amdgcn_mfma_f32_16x16x32_bf16(
                    aF[mt], bF[nt], acc[mt][nt], 0, 0, 0);
    }

#pragma unroll
    for (int mt = 0; mt < 4; ++mt)
#pragma unroll
        for (int nt = 0; nt < 4; ++nt) {
            int gr = row0 + wm + mt * 16 + quad * 4;
            int gc = col0 + wn + nt * 16 + l16;
#pragma unroll
            for (int reg = 0; reg < 4; ++reg)
                store_multi(gr + reg, gc, acc[mt][nt][reg], qkv, z, a_out, b_out);
        }
}

// ================= out-projection MFMA GEMM =================
__global__ __launch_bounds__(256) void gemm_outproj(
    const unsigned short* __restrict__ A,   // (ROWS, VAL_DIM) bf16
    const float* __restrict__ W,            // (DIM, VAL_DIM) f32
    float* __restrict__ C)                  // (ROWS, DIM) f32
{
    __shared__ __align__(16) unsigned short As[128 * SA];
    __shared__ __align__(16) unsigned short Ws[128 * SA];

    const int t    = threadIdx.x;
    const int row0 = blockIdx.y * 128;
    const int col0 = blockIdx.x * 128;
    const int r    = t >> 1;
    const int kh   = (t & 1) * 16;
    const int lane = t & 63;
    const int wid  = t >> 6;
    const int wm   = (wid >> 1) * 64;
    const int wn   = (wid & 1) * 64;
    const int quad = lane >> 4;
    const int l16  = lane & 15;

    ffrag acc[4][4];
#pragma unroll
    for (int i = 0; i < 4; ++i)
#pragma unroll
        for (int j = 0; j < 4; ++j) acc[i][j] = (ffrag)0.f;

    const unsigned short* aP = A + (size_t)(row0 + r) * VAL_DIM + kh;
    const float* wP = W + (size_t)(col0 + r) * VAL_DIM + kh;

    const int aoff = r * SA + kh;
    const int fa   = (wm + l16) * SA + quad * 8;
    const int fb   = (wn + l16) * SA + quad * 8;

    for (int k0 = 0; k0 < VAL_DIM; k0 += 32) {
        uint4 au0 = *(const uint4*)(aP + k0);
        uint4 au1 = *(const uint4*)(aP + k0 + 8);
        float4 wv0 = *(const float4*)(wP + k0);
        float4 wv1 = *(const float4*)(wP + k0 + 4);
        float4 wv2 = *(const float4*)(wP + k0 + 8);
        float4 wv3 = *(const float4*)(wP + k0 + 12);
        __syncthreads();
        *(uint4*)&As[aoff]     = au0;
        *(uint4*)&As[aoff + 8] = au1;
        *(uint4*)&Ws[aoff]     = make_uint4(pk2(wv0.x, wv0.y), pk2(wv0.z, wv0.w),
                                            pk2(wv1.x, wv1.y), pk2(wv1.z, wv1.w));
        *(uint4*)&Ws[aoff + 8] = make_uint4(pk2(wv2.x, wv2.y), pk2(wv2.z, wv2.w),
                                            pk2(wv3.x, wv3.y), pk2(wv3.z, wv3.w));
        __syncthreads();

        bfrag aF[4], bF[4];
#pragma unroll
        for (int mt = 0; mt < 4; ++mt) aF[mt] = *(const bfrag*)&As[fa + mt * 16 * SA];
#pragma unroll
        for (int nt = 0; nt < 4; ++nt) bF[nt] = *(const bfrag*)&Ws[fb + nt * 16 * SA];
#pragma unroll
        for (int mt = 0; mt < 4; ++mt)
#pragma unroll
            for (int nt = 0; nt < 4; ++nt)
                acc[mt][nt] = __builtin_amdgcn_mfma_f32_16x16x32_bf16(
                    aF[mt], bF[nt], acc[mt][nt], 0, 0, 0);
    }

#pragma unroll
    for (int mt = 0; mt < 4; ++mt)
#pragma unroll
        for (int nt = 0; nt < 4; ++nt) {
            int gr = row0 + wm + mt * 16 + quad * 4;
            int gc = col0 + wn + nt * 16 + l16;
#pragma unroll
            for (int reg = 0; reg < 4; ++reg)
                C[(size_t)(gr + reg) * DIM + gc] = acc[mt][nt][reg];
        }
}

// ================= depthwise causal conv1d + SiLU =================
__global__ __launch_bounds__(256) void conv_silu(unsigned short* __restrict__ qkv,
                                                 const float* __restrict__ conv_w)
{
    int idx = blockIdx.x * blockDim.x + threadIdx.x;
    int b = idx >> 13;
    int c = idx & (CONV_DIM - 1);
    const float w0 = conv_w[c * 4 + 0];
    const float w1 = conv_w[c * 4 + 1];
    const float w2 = conv_w[c * 4 + 2];
    const float w3 = conv_w[c * 4 + 3];
    unsigned short* p = qkv + (size_t)b * L * CONV_DIM + c;
    float x0 = 0.f, x1 = 0.f, x2 = 0.f;
    for (int l0 = 0; l0 < L; l0 += 8) {
        float xv[8];
#pragma unroll
        for (int j = 0; j < 8; ++j) xv[j] = bf2f(p[(size_t)(l0 + j) * CONV_DIM]);
#pragma unroll
        for (int j = 0; j < 8; ++j) {
            float h = w0 * x0 + w1 * x1 + w2 * x2 + w3 * xv[j];
            float s = h / (1.f + __expf(-h));
            p[(size_t)(l0 + j) * CONV_DIM] = f2bf(s);
            x0 = x1; x1 = x2; x2 = xv[j];
        }
    }
}

// ================= l2norm of q,k heads =================
__global__ __launch_bounds__(256) void normqk(unsigned short* __restrict__ qkv)
{
    int wid  = blockIdx.x * 4 + (threadIdx.x >> 6);
    int lane = threadIdx.x & 63;
    int hk  = wid & 15;
    int sel = (wid >> 4) & 1;
    int row = wid >> 5;
    unsigned short* p = qkv + (size_t)row * CONV_DIM + sel * KEY_DIM + hk * DK;
    float x0 = bf2f(p[lane]), x1 = bf2f(p[lane + 64]);
    float ss = x0 * x0 + x1 * x1;
#pragma unroll
    for (int o = 32; o >= 1; o >>= 1) ss += __shfl_xor(ss, o);
    float sc = rsqrtf(ss + 1e-6f);
    if (sel == 0) sc *= 0.08838834764831845f;   // DK^-0.5
    p[lane]      = f2bf(x0 * sc);
    p[lane + 64] = f2bf(x1 * sc);
}

// ================= gate coefficients: g (log) and beta =================
__global__ __launch_bounds__(256) void gatecoef(const float* __restrict__ a_buf,
                                                const float* __restrict__ b_buf,
                                                const float* __restrict__ A_log,
                                                const float* __restrict__ dt_bias,
                                                float* __restrict__ glog,
                                                float* __restrict__ beta)
{
    int idx = blockIdx.x * blockDim.x + threadIdx.x;
    int h = idx & (HV - 1);
    float av = a_buf[idx];
    float bv = b_buf[idx];
    float x  = av + dt_bias[h];
    float sp = (x > 20.f) ? x : log1pf(__expf(x));
    glog[idx] = -__expf(A_log[h]) * sp;
    beta[idx] = 1.f / (1.f + __expf(-bv));
}

// ================= chunked gated delta rule (WY form) =================
// One block per (b,h). 4 waves. Chunk C=64. State (dk x dv transposed:
// ST[dv][dk]) lives in MFMA accumulator registers, bf16 copy in LDS.
// Per chunk:  A = beta_i e^{Gi-Gj}(k_i.k_j) [j<i];  (I+A) Delta = B(V - G*(K S0))
//             O = G*(Q S0) + (masked e^{Gi-Gj} QK^T) Delta  (fused RMSNorm+gate)
//             ST <- e^{Gc} ST + Dd^T KT    (Dd_j = e^{Gc-Gj} delta_j)

// LDS strides (bf16 elems unless noted)
constexpr int RSK = 136;   // Ks/Qs/STb rows (128 data + 8 pad)
constexpr int RST = 72;    // KT/Af/Wb/DT/DdT rows (64 data + 8 pad)
constexpr int RSR = 132;   // RHS row stride (f32)

constexpr int oKs  = 0;                       // 64*136*2  = 17408
constexpr int oQs  = oKs  + 64 * RSK * 2;     // 17408
constexpr int oKT  = oQs  + 64 * RSK * 2;     // 128*72*2  = 18432
constexpr int oAf  = oKT  + 128 * RST * 2;    // 64*72*2   = 9216
constexpr int oR1  = oAf  + 64 * RST * 2;     // union: STb(34816) | Wb+DT+DdT(46080)
constexpr int oWb  = oR1;
constexpr int oDT  = oR1  + 64 * RST * 2;     // +9216
constexpr int oDdT = oDT  + 128 * RST * 2;    // +18432
constexpr int oRHS = oR1  + 46080;            // 64*132*4 = 33792
constexpr int oG   = oRHS + 64 * RSR * 4;
constexpr int oEG  = oG   + 256;
constexpr int oBs  = oEG  + 256;
constexpr int oNW  = oBs  + 256;
constexpr int SMEM_BYTES = oNW + 512;         // = 143616

__global__ __launch_bounds__(256, 1) void chunk_scan(
    const unsigned short* __restrict__ qkv,
    const float* __restrict__ glog,
    const float* __restrict__ beta,
    unsigned short* __restrict__ z_io,
    const float* __restrict__ norm_w)
{
    extern __shared__ __align__(16) char smem[];
    unsigned short* sKs  = (unsigned short*)(smem + oKs);
    unsigned short* sQs  = (unsigned short*)(smem + oQs);
    unsigned short* sKT  = (unsigned short*)(smem + oKT);
    unsigned short* sAf  = (unsigned short*)(smem + oAf);
    unsigned short* sSTb = (unsigned short*)(smem + oR1);
    unsigned short* sWb  = (unsigned short*)(smem + oWb);
    unsigned short* sDT  = (unsigned short*)(smem + oDT);
    unsigned short* sDdT = (unsigned short*)(smem + oDdT);
    float* sRHS = (float*)(smem + oRHS);
    float* sG   = (float*)(smem + oG);
    float* sEG  = (float*)(smem + oEG);
    float* sBs  = (float*)(smem + oBs);
    float* sNW  = (float*)(smem + oNW);

    const int bb = blockIdx.x >> 5;
    const int h  = blockIdx.x & (HV - 1);
    const int hk = h >> 1;
    const int t    = threadIdx.x;
    const int w    = t >> 6;
    const int lane = t & 63;
    const int quad = lane >> 4;
    const int l16  = lane & 15;
    const int quad8 = quad * 8;
    const size_t bL = (size_t)bb * L;
    const int VOFF = 2 * KEY_DIM + h * DV;

    // persistent state accumulators: ST[dv][dk], wave w owns dv in [32w,32w+32)
    ffrag accS[2][8];
#pragma unroll
    for (int mt = 0; mt < 2; ++mt)
#pragma unroll
        for (int nt = 0; nt < 8; ++nt) accS[mt][nt] = (ffrag)0.f;

    // init: zero STb, load norm weights
    for (int u = t; u < 64 * RSK; u += 256) ((uint32_t*)sSTb)[u] = 0;  // 128*136 bf16
    if (t < 128) sNW[t] = norm_w[t];

    for (int ch = 0; ch < NCHUNK; ++ch) {
        const int l0 = ch * CHUNK;
        __syncthreads();   // S0: prev STb written; safe to overwrite Ks/Qs/KT/gates

        // ---- load phase ----
        {
            const int r  = t >> 2;
            const int c0 = (t & 3) * 32;
            const unsigned short* grow = qkv + (bL + l0 + r) * CONV_DIM;
            const unsigned short* gq = grow + hk * DK + c0;
            const unsigned short* gk = grow + KEY_DIM + hk * DK + c0;
#pragma unroll
            for (int u = 0; u < 4; ++u) {
                uint4 kv = *(const uint4*)(gk + 8 * u);
                uint4 qv = *(const uint4*)(gq + 8 * u);
                *(uint4*)&sKs[r * RSK + c0 + 8 * u] = kv;
                *(uint4*)&sQs[r * RSK + c0 + 8 * u] = qv;
                const unsigned short* kp = (const unsigned short*)&kv;
#pragma unroll
                for (int e = 0; e < 8; ++e)
                    sKT[(c0 + 8 * u + e) * RST + r] = kp[e];
            }
            if (t < 64) {
                float gl = glog[(bL + l0 + t) * HV + h];
#pragma unroll
                for (int off = 1; off < 64; off <<= 1) {
                    float v = __shfl_up(gl, off, 64);
                    if (lane >= off) gl += v;
                }
                sG[t]  = gl;
                sEG[t] = __expf(gl);
                sBs[t] = beta[(bL + l0 + t) * HV + h];
            }
        }
        __syncthreads();   // S1

        // ---- MFMA phase: A, RHS, QS0 (regs), W (regs) ----
        ffrag accO[8];
        ffrag accW[4];
        {
            // A = K K^T  (wave w: cols j in [16w,16w+16))
            ffrag accA[4];
#pragma unroll
            for (int mt = 0; mt < 4; ++mt) accA[mt] = (ffrag)0.f;
#pragma unroll
            for (int kk = 0; kk < 4; ++kk) {
                bfrag bf = *(const bfrag*)&sKs[(16 * w + l16) * RSK + 32 * kk + quad8];
#pragma unroll
                for (int mt = 0; mt < 4; ++mt) {
                    bfrag af = *(const bfrag*)&sKs[(16 * mt + l16) * RSK + 32 * kk + quad8];
                    accA[mt] = __builtin_amdgcn_mfma_f32_16x16x32_bf16(af, bf, accA[mt], 0, 0, 0);
                }
            }
            const int j = 16 * w + l16;
            const float gj = sG[j];
#pragma unroll
            for (int mt = 0; mt < 4; ++mt)
#pragma unroll
                for (int reg = 0; reg < 4; ++reg) {
                    int i = 16 * mt + quad * 4 + reg;
                    float v = (j < i) ? sBs[i] * __expf(sG[i] - gj) * accA[mt][reg] : 0.f;
                    sAf[i * RST + j] = f2bf(v);
                }

            // RHS = B(V - eG*(K STb^T-read))   (wave w: dv in [32w,32w+32))
            ffrag accR[4][2];
#pragma unroll
            for (int mt = 0; mt < 4; ++mt)
#pragma unroll
                for (int nt = 0; nt < 2; ++nt) accR[mt][nt] = (ffrag)0.f;
#pragma unroll
            for (int kk = 0; kk < 4; ++kk) {
                bfrag b0 = *(const bfrag*)&sSTb[(32 * w + l16) * RSK + 32 * kk + quad8];
                bfrag b1 = *(const bfrag*)&sSTb[(32 * w + 16 + l16) * RSK + 32 * kk + quad8];
#pragma unroll
                for (int mt = 0; mt < 4; ++mt) {
                    bfrag af = *(const bfrag*)&sKs[(16 * mt + l16) * RSK + 32 * kk + quad8];
                    accR[mt][0] = __builtin_amdgcn_mfma_f32_16x16x32_bf16(af, b0, accR[mt][0], 0, 0, 0);
                    accR[mt][1] = __builtin_amdgcn_mfma_f32_16x16x32_bf16(af, b1, accR[mt][1], 0, 0, 0);
                }
            }
#pragma unroll
            for (int mt = 0; mt < 4; ++mt)
#pragma unroll
                for (int nt = 0; nt < 2; ++nt)
#pragma unroll
                    for (int reg = 0; reg < 4; ++reg) {
                        int i  = 16 * mt + quad * 4 + reg;
                        int dv = 32 * w + 16 * nt + l16;
                        float vv = bf2f(qkv[(bL + l0 + i) * CONV_DIM + VOFF + dv]);
                        sRHS[i * RSR + dv] = sBs[i] * (vv - sEG[i] * accR[mt][nt][reg]);
                    }

            // QS0 (wave w: rows i in [16w,16w+16), all dv) -> accO regs
#pragma unroll
            for (int nt = 0; nt < 8; ++nt) accO[nt] = (ffrag)0.f;
#pragma unroll
            for (int kk = 0; kk < 4; ++kk) {
                bfrag af = *(const bfrag*)&sQs[(16 * w + l16) * RSK + 32 * kk + quad8];
#pragma unroll
                for (int nt = 0; nt < 8; ++nt) {
                    bfrag bf = *(const bfrag*)&sSTb[(16 * nt + l16) * RSK + 32 * kk + quad8];
                    accO[nt] = __builtin_amdgcn_mfma_f32_16x16x32_bf16(af, bf, accO[nt], 0, 0, 0);
                }
            }
#pragma unroll
            for (int nt = 0; nt < 8; ++nt)
#pragma unroll
                for (int reg = 0; reg < 4; ++reg)
                    accO[nt][reg] *= sEG[16 * w + quad * 4 + reg];

            // W = Q K^T masked/scaled  (wave w: cols j in [16w,16w+16)) -> regs
#pragma unroll
            for (int mt = 0; mt < 4; ++mt) accW[mt] = (ffrag)0.f;
#pragma unroll
            for (int kk = 0; kk < 4; ++kk) {
                bfrag bf = *(const bfrag*)&sKs[(16 * w + l16) * RSK + 32 * kk + quad8];
#pragma unroll
                for (int mt = 0; mt < 4; ++mt) {
                    bfrag af = *(const bfrag*)&sQs[(16 * mt + l16) * RSK + 32 * kk + quad8];
                    accW[mt] = __builtin_amdgcn_mfma_f32_16x16x32_bf16(af, bf, accW[mt], 0, 0, 0);
                }
            }
#pragma unroll
            for (int mt = 0; mt < 4; ++mt)
#pragma unroll
                for (int reg = 0; reg < 4; ++reg) {
                    int i = 16 * mt + quad * 4 + reg;
                    accW[mt][reg] = (j <= i) ? __expf(sG[i] - gj) * accW[mt][reg] : 0.f;
                }
        }
        __syncthreads();   // S2: STb reads done; R1 free

        // ---- write Wb; zero DT (padding cols read by block-solve MFMAs) ----
        {
            const int j = 16 * w + l16;
#pragma unroll
            for (int mt = 0; mt < 4; ++mt)
#pragma unroll
                for (int reg = 0; reg < 4; ++reg)
                    sWb[(16 * mt + quad * 4 + reg) * RST + j] = f2bf(accW[mt][reg]);
            for (int u = t; u < 64 * RST; u += 256) ((uint32_t*)sDT)[u] = 0;  // 128*72 bf16
        }
        __syncthreads();   // S3

        // ---- blocked forward substitution: (I+A) Delta = RHS ----
        const float gc = sG[63];
        for (int sb = 0; sb < 4; ++sb) {
            const int sb16 = 16 * sb;
            // (a) RHS[sb-block] -= A[sb,<sb] * Delta  (MFMA, K padded w/ zeros)
            if (sb > 0) {
                const int kbn = (sb + 1) >> 1;
                ffrag c16[2];
                c16[0] = (ffrag)0.f; c16[1] = (ffrag)0.f;
                for (int kb = 0; kb < kbn; ++kb) {
                    bfrag af = *(const bfrag*)&sAf[(sb16 + l16) * RST + 32 * kb + quad8];
                    bfrag b0 = *(const bfrag*)&sDT[(32 * w + l16) * RST + 32 * kb + quad8];
                    bfrag b1 = *(const bfrag*)&sDT[(32 * w + 16 + l16) * RST + 32 * kb + quad8];
                    c16[0] = __builtin_amdgcn_mfma_f32_16x16x32_bf16(af, b0, c16[0], 0, 0, 0);
                    c16[1] = __builtin_amdgcn_mfma_f32_16x16x32_bf16(af, b1, c16[1], 0, 0, 0);
                }
#pragma unroll
                for (int nt = 0; nt < 2; ++nt)
#pragma unroll
                    for (int reg = 0; reg < 4; ++reg) {
                        int i  = sb16 + quad * 4 + reg;
                        int dv = 32 * w + 16 * nt + l16;
                        sRHS[i * RSR + dv] -= c16[nt][reg];
                    }
            }
            __syncthreads();
            // (b) 16x16 unit-lower-triangular solve, thread c owns column c
            if (t < 128) {
                const int c = t;
                float d16[16];
#pragma unroll
                for (int e = 0; e < 16; ++e) {
                    const int i = sb16 + e;
                    float acc = sRHS[i * RSR + c];
#pragma unroll
                    for (int f = 0; f < 16; ++f)
                        if (f < e) acc -= bf2f(sAf[i * RST + sb16 + f]) * d16[f];
                    d16[e] = acc;
                }
#pragma unroll
                for (int e = 0; e < 16; e += 2) {
                    const int jj = sb16 + e;
                    *(uint32_t*)&sDT[c * RST + jj] = pk2(d16[e], d16[e + 1]);
                    float s0 = __expf(gc - sG[jj]);
                    float s1 = __expf(gc - sG[jj + 1]);
                    *(uint32_t*)&sDdT[c * RST + jj] = pk2(d16[e] * s0, d16[e + 1] * s1);
                }
            }
            __syncthreads();
        }

        // ---- O = accO + W*Delta ; fused gated RMSNorm ; state update ----
        {
            ffrag accO2[8];
#pragma unroll
            for (int nt = 0; nt < 8; ++nt) accO2[nt] = accO[nt];
#pragma unroll
            for (int kk = 0; kk < 2; ++kk) {
                bfrag af = *(const bfrag*)&sWb[(16 * w + l16) * RST + 32 * kk + quad8];
#pragma unroll
                for (int nt = 0; nt < 8; ++nt) {
                    bfrag bf = *(const bfrag*)&sDT[(16 * nt + l16) * RST + 32 * kk + quad8];
                    accO2[nt] = __builtin_amdgcn_mfma_f32_16x16x32_bf16(af, bf, accO2[nt], 0, 0, 0);
                }
            }
            // RMSNorm over dv + silu(z) gate, write y over z
            float inv[4];
#pragma unroll
            for (int reg = 0; reg < 4; ++reg) {
                float p = 0.f;
#pragma unroll
                for (int nt = 0; nt < 8; ++nt) p += accO2[nt][reg] * accO2[nt][reg];
#pragma unroll
                for (int m = 1; m < 16; m <<= 1) p += __shfl_xor(p, m, 64);
                inv[reg] = rsqrtf(p * (1.f / 128.f) + EPS);
            }
            const int i0 = 16 * w + quad * 4;
#pragma unroll
            for (int nt = 0; nt < 8; ++nt) {
                const int dv = 16 * nt + l16;
                const float nwv = sNW[dv];
#pragma unroll
                for (int reg = 0; reg < 4; ++reg) {
                    size_t zi = (bL + l0 + i0 + reg) * (size_t)VAL_DIM + h * DV + dv;
                    float zv = bf2f(z_io[zi]);
                    float y = accO2[nt][reg] * inv[reg] * nwv * (zv / (1.f + __expf(-zv)));
                    z_io[zi] = f2bf(y);
                }
            }

            // state update: ST = eGc*ST + DdT * KT^T-read
            const float eGc = sEG[63];
#pragma unroll
            for (int mt = 0; mt < 2; ++mt)
#pragma unroll
                for (int nt = 0; nt < 8; ++nt)
#pragma unroll
                    for (int reg = 0; reg < 4; ++reg) accS[mt][nt][reg] *= eGc;
#pragma unroll
            for (int kk = 0; kk < 2; ++kk) {
                bfrag a0 = *(const bfrag*)&sDdT[(32 * w + l16) * RST + 32 * kk + quad8];
                bfrag a1 = *(const bfrag*)&sDdT[(32 * w + 16 + l16) * RST + 32 * kk + quad8];
#pragma unroll
                for (int nt = 0; nt < 8; ++nt) {
                    bfrag bk = *(const bfrag*)&sKT[(16 * nt + l16) * RST + 32 * kk + quad8];
                    accS[0][nt] = __builtin_amdgcn_mfma_f32_16x16x32_bf16(a0, bk, accS[0][nt], 0, 0, 0);
                    accS[1][nt] = __builtin_amdgcn_mfma_f32_16x16x32_bf16(a1, bk, accS[1][nt], 0, 0, 0);
                }
            }
        }
        __syncthreads();   // S4: DT/DdT/Wb reads done; R1 free for STb

        // ---- materialize STb (bf16) for next chunk ----
#pragma unroll
        for (int mt = 0; mt < 2; ++mt)
#pragma unroll
            for (int nt = 0; nt < 8; ++nt)
#pragma unroll
                for (int reg = 0; reg < 4; ++reg)
                    sSTb[(32 * w + 16 * mt + quad * 4 + reg) * RSK + 16 * nt + l16] =
                        f2bf(accS[mt][nt][reg]);
    }
}

// ---------------- launch ----------------
extern "C" void kernel_launch(void* const* d_in, const int* in_sizes, int n_in,
                              void* d_out, int out_size, void* d_ws, size_t ws_size,
                              hipStream_t stream)
{
    const float* x        = (const float*)d_in[0];
    const float* W_qkv    = (const float*)d_in[1];
    const float* W_z      = (const float*)d_in[2];
    const float* W_a      = (const float*)d_in[3];
    const float* W_b      = (const float*)d_in[4];
    const float* conv_w   = (const float*)d_in[5];
    const float* A_log    = (const float*)d_in[6];
    const float* dt_bias  = (const float*)d_in[7];
    const float* norm_w   = (const float*)d_in[8];
    const float* W_out    = (const float*)d_in[9];
    float* out = (float*)d_out;
    char*  ws  = (char*)d_ws;

    if (ws_size < WS_NEED_BYTES) return;

    unsigned short* qkv = (unsigned short*)(ws + OFF_QKV);
    unsigned short* z   = (unsigned short*)(ws + OFF_Z);
    float* a    = (float*)(ws + OFF_A);
    float* bbuf = (float*)(ws + OFF_B);
    float* gl   = (float*)(ws + OFF_G);
    float* beta = (float*)(ws + OFF_BETA);

    static bool attr_set = false;
    if (!attr_set) {
        (void)hipFuncSetAttribute((const void*)chunk_scan,
                                  hipFuncAttributeMaxDynamicSharedMemorySize, SMEM_BYTES);
        attr_set = true;
    }

    // 1. fused input projections (MFMA bf16)
    dim3 g1((NPROJ + 127) / 128, ROWS / 128);
    gemm_inproj<<<g1, 256, 0, stream>>>(x, W_qkv, W_z, W_a, W_b, qkv, z, a, bbuf);
    // 2. depthwise causal conv + silu
    conv_silu<<<(B * CONV_DIM) / 256, 256, 0, stream>>>(qkv, conv_w);
    // 3. l2norm q,k heads
    normqk<<<(B * L * 2 * HK) / 4, 256, 0, stream>>>(qkv);
    // 4. gate coefficients (log-space g)
    gatecoef<<<(B * L * HV) / 256, 256, 0, stream>>>(a, bbuf, A_log, dt_bias, gl, beta);
    // 5. chunked delta rule + fused gated RMSNorm (y overwrites z)
    chunk_scan<<<B * HV, 256, SMEM_BYTES, stream>>>(qkv, gl, beta, z, norm_w);
    // 6. output projection (MFMA bf16)
    dim3 g2(DIM / 128, ROWS / 128);
    gemm_outproj<<<g2, 256, 0, stream>>>(z, W_out, out);
}